// Round 1
// baseline (257.800 us; speedup 1.0000x reference)
//
#include <hip/hip_runtime.h>

#define NN 8192      // rows == cols
#define DD 64        // inner dim
#define RPB 8        // rows per block
#define CPT 8        // cols per thread
#define NT 1024      // threads per block
#define NWAVE (NT / 64)
#define NBINS 128
#define LCAP 64
#define WINDOW 12.0f // values below rowmax-12 contribute < 6e-6 to any output

__global__ __launch_bounds__(NT) void sag_fused(
    const float* __restrict__ nv1,
    const float* __restrict__ nv2,
    const int* __restrict__ topkp,
    float* __restrict__ out)
{
    __shared__ float a1t[DD][RPB];          // nodevec1 tile, transposed [d][r]
    __shared__ int   hist[RPB][NBINS];
    __shared__ float blist[RPB][LCAP];      // boundary-bin candidate values
    __shared__ int   bcount[RPB];
    __shared__ float mpart[RPB][NWAVE];
    __shared__ float zpart[RPB][NWAVE];
    __shared__ int   cpart[RPB][NWAVE];
    __shared__ float m_f[RPB];              // row max (>=0 after relu)
    __shared__ float tsel[RPB];             // strict selection threshold: keep v > tsel
    __shared__ float zsum[RPB];             // sum of exp(v-m) over selected
    __shared__ int   scnt[RPB];             // selected count
    __shared__ int   binb[RPB];             // boundary bin (-1 => take whole window)
    __shared__ int   needv[RPB];            // how many to take from boundary bin

    const int tid  = threadIdx.x;
    const int wv   = tid >> 6;
    const int ln   = tid & 63;
    const int row0 = blockIdx.x * RPB;
    const int K    = topkp[0];

    // ---- stage nodevec1 rows (transposed) + init LDS ----
    if (tid < DD * RPB) {
        const int d = tid >> 3, r = tid & 7;
        a1t[d][r] = nv1[(row0 + r) * DD + d];
    }
    for (int i = tid; i < RPB * NBINS; i += NT) (&hist[0][0])[i] = 0;
    if (tid < RPB) bcount[tid] = 0;
    __syncthreads();

    // ---- scoring: s[r][c] = nodevec1[row0+r] . nodevec2[:, col0+c] ----
    float s[RPB][CPT];
    #pragma unroll
    for (int r = 0; r < RPB; ++r)
        #pragma unroll
        for (int c = 0; c < CPT; ++c) s[r][c] = 0.f;

    const int col0 = tid * CPT;
    const float* p2 = nv2 + col0;
    #pragma unroll 2
    for (int d = 0; d < DD; ++d) {
        const float4 b0 = *reinterpret_cast<const float4*>(p2);
        const float4 b1 = *reinterpret_cast<const float4*>(p2 + 4);
        const float4 a0 = *reinterpret_cast<const float4*>(&a1t[d][0]);
        const float4 a4 = *reinterpret_cast<const float4*>(&a1t[d][4]);
        const float av[RPB] = {a0.x, a0.y, a0.z, a0.w, a4.x, a4.y, a4.z, a4.w};
        #pragma unroll
        for (int r = 0; r < RPB; ++r) {
            s[r][0] = fmaf(av[r], b0.x, s[r][0]);
            s[r][1] = fmaf(av[r], b0.y, s[r][1]);
            s[r][2] = fmaf(av[r], b0.z, s[r][2]);
            s[r][3] = fmaf(av[r], b0.w, s[r][3]);
            s[r][4] = fmaf(av[r], b1.x, s[r][4]);
            s[r][5] = fmaf(av[r], b1.y, s[r][5]);
            s[r][6] = fmaf(av[r], b1.z, s[r][6]);
            s[r][7] = fmaf(av[r], b1.w, s[r][7]);
        }
        p2 += NN;
    }

    // ---- relu + row max (deterministic tree) ----
    #pragma unroll
    for (int r = 0; r < RPB; ++r) {
        float mx = 0.f;
        #pragma unroll
        for (int c = 0; c < CPT; ++c) {
            s[r][c] = fmaxf(s[r][c], 0.f);
            mx = fmaxf(mx, s[r][c]);
        }
        #pragma unroll
        for (int off = 32; off; off >>= 1) mx = fmaxf(mx, __shfl_xor(mx, off));
        if (ln == 0) mpart[r][wv] = mx;
    }
    __syncthreads();
    if (tid < RPB) {
        float mm = 0.f;
        for (int w = 0; w < NWAVE; ++w) mm = fmaxf(mm, mpart[tid][w]);
        m_f[tid] = mm;
    }
    __syncthreads();

    // ---- histogram of values in window (lb, m] ----
    const float invw = (float)NBINS / WINDOW;
    #pragma unroll
    for (int r = 0; r < RPB; ++r) {
        const float lbr = fmaxf(m_f[r] - WINDOW, 0.f);
        #pragma unroll
        for (int c = 0; c < CPT; ++c) {
            const float v = s[r][c];
            if (v > lbr) {
                int bi = (int)((v - lbr) * invw);
                bi = bi < NBINS - 1 ? bi : NBINS - 1;
                atomicAdd(&hist[r][bi], 1);
            }
        }
    }
    __syncthreads();

    // ---- scan: find boundary bin where cumulative (from top) reaches K ----
    if (tid < RPB) {
        int cum = 0, b = -1, nd = 0;
        for (int i = NBINS - 1; i >= 0; --i) {
            const int h = hist[tid][i];
            if (cum + h >= K) { b = i; nd = K - cum; break; }
            cum += h;
        }
        binb[tid]  = b;
        needv[tid] = nd;
        if (b < 0) tsel[tid] = fmaxf(m_f[tid] - WINDOW, 0.f); // < K values in window: keep them all
    }
    __syncthreads();

    // ---- collect boundary-bin values ----
    #pragma unroll
    for (int r = 0; r < RPB; ++r) {
        const int b = binb[r];
        if (b >= 0) {
            const float lbr = fmaxf(m_f[r] - WINDOW, 0.f);
            #pragma unroll
            for (int c = 0; c < CPT; ++c) {
                const float v = s[r][c];
                if (v > lbr) {
                    int bi = (int)((v - lbr) * invw);
                    bi = bi < NBINS - 1 ? bi : NBINS - 1;
                    if (bi == b) {
                        const int p = atomicAdd(&bcount[r], 1);
                        if (p < LCAP) blist[r][p] = v;
                    }
                }
            }
        }
    }
    __syncthreads();

    // ---- exact rank within boundary bin: wave w refines row w ----
    if (wv < RPB) {
        const int r = wv;
        if (binb[r] >= 0) {
            const int n  = min(bcount[r], LCAP);
            const int nd = needv[r];
            const float v = (ln < n) ? blist[r][ln] : -1.f;
            int rank = 0;
            for (int j = 0; j < LCAP; ++j) {
                const float vj = __shfl(v, j);
                rank += (vj > v) ? 1 : 0;
            }
            float cand = (ln < n && rank < nd) ? v : 3.4e38f;
            #pragma unroll
            for (int off = 32; off; off >>= 1) cand = fminf(cand, __shfl_xor(cand, off));
            if (ln == 0) tsel[r] = __int_as_float(__float_as_int(cand) - 1); // just below nd-th largest
        }
    }
    __syncthreads();

    // ---- exp encode (sign marks selection) + deterministic Z reduction ----
    #pragma unroll
    for (int r = 0; r < RPB; ++r) {
        const float mr = m_f[r];
        const float t  = tsel[r];
        float part = 0.f;
        int   cnt  = 0;
        #pragma unroll
        for (int c = 0; c < CPT; ++c) {
            const float v  = s[r][c];
            const bool sel = v > t;
            const float e  = __expf(v - mr);
            part += sel ? e : 0.f;
            cnt  += sel ? 1 : 0;
            s[r][c] = sel ? e : -e;
        }
        #pragma unroll
        for (int off = 32; off; off >>= 1) {
            part += __shfl_xor(part, off);
            cnt  += __shfl_xor(cnt, off);
        }
        if (ln == 0) { zpart[r][wv] = part; cpart[r][wv] = cnt; }
    }
    __syncthreads();
    if (tid < RPB) {
        float z = 0.f; int c2 = 0;
        for (int w = 0; w < NWAVE; ++w) { z += zpart[tid][w]; c2 += cpart[tid][w]; }
        zsum[tid] = z; scnt[tid] = c2;
    }
    __syncthreads();

    // ---- write output: selected -> exp(v-m)/Z, else exp(-m)/Z ----
    #pragma unroll
    for (int r = 0; r < RPB; ++r) {
        const float mr   = m_f[r];
        const float e0   = __expf(-mr);
        const float Z    = zsum[r] + (float)(NN - scnt[r]) * e0;
        const float invZ = 1.0f / Z;
        float4 o0, o1;
        o0.x = (s[r][0] > 0.f ? s[r][0] : e0) * invZ;
        o0.y = (s[r][1] > 0.f ? s[r][1] : e0) * invZ;
        o0.z = (s[r][2] > 0.f ? s[r][2] : e0) * invZ;
        o0.w = (s[r][3] > 0.f ? s[r][3] : e0) * invZ;
        o1.x = (s[r][4] > 0.f ? s[r][4] : e0) * invZ;
        o1.y = (s[r][5] > 0.f ? s[r][5] : e0) * invZ;
        o1.z = (s[r][6] > 0.f ? s[r][6] : e0) * invZ;
        o1.w = (s[r][7] > 0.f ? s[r][7] : e0) * invZ;
        float* po = out + (size_t)(row0 + r) * NN + col0;
        *reinterpret_cast<float4*>(po)     = o0;
        *reinterpret_cast<float4*>(po + 4) = o1;
    }
}

extern "C" void kernel_launch(void* const* d_in, const int* in_sizes, int n_in,
                              void* d_out, int out_size, void* d_ws, size_t ws_size,
                              hipStream_t stream) {
    const float* nv1   = (const float*)d_in[0];
    const float* nv2   = (const float*)d_in[1];
    const int*   topkp = (const int*)d_in[2];
    float*       out   = (float*)d_out;
    dim3 grid(NN / RPB), block(NT);
    hipLaunchKernelGGL(sag_fused, grid, block, 0, stream, nv1, nv2, topkp, out);
}